// Round 2
// baseline (1633.714 us; speedup 1.0000x reference)
//
#include <hip/hip_runtime.h>

typedef unsigned short u16;
typedef unsigned int u32;

#define HWSZ 40000
#define NB 40

__device__ __forceinline__ float bf2f(u16 x) {
  union { u32 u; float f; } c; c.u = ((u32)x) << 16; return c.f;
}
__device__ __forceinline__ float bflo(u32 u) {
  union { u32 u; float f; } c; c.u = u << 16; return c.f;
}
__device__ __forceinline__ float bfhi(u32 u) {
  union { u32 u; float f; } c; c.u = u & 0xffff0000u; return c.f;
}
__device__ __forceinline__ u16 f2bf(float f) {
  union { float f; u32 u; } c; c.f = f;
  u32 r = c.u + 0x7fffu + ((c.u >> 16) & 1u);
  return (u16)(r >> 16);
}

// ---------------- K0: weight transpose (fp32 -> fp32, [co][ci] -> [ci][co]) ----------------
__global__ __launch_bounds__(256) void k_tw(
    const float* __restrict__ Wmap, const float* __restrict__ Wq,
    const float* __restrict__ Wk, const float* __restrict__ Wv,
    float* __restrict__ wmapT, float* __restrict__ wqT,
    float* __restrict__ wkT, float* __restrict__ wvT) {
  int which = blockIdx.y;
  const float* src; float* dst; int IC;
  if (which == 0)      { src = Wmap; dst = wmapT; IC = 512; }
  else if (which == 1) { src = Wq;   dst = wqT;   IC = 256; }
  else if (which == 2) { src = Wk;   dst = wkT;   IC = 256; }
  else                 { src = Wv;   dst = wvT;   IC = 256; }
  int idx = blockIdx.x * 256 + threadIdx.x;
  if (idx < IC * 256) {
    int co = idx & 255, ci = idx >> 8;
    dst[idx] = src[co * IC + ci];  // dst[ci][co]
  }
}

// ---------------- K1a: n_aux = relu(W_map @ [noisy;aux] + b) ----------------
// n_aux stored fp32, channel-major [b][co][hw]
__global__ __launch_bounds__(256) void k_naux(
    const float* __restrict__ noisy, const float* __restrict__ aux,
    const float* __restrict__ wmapT, const float* __restrict__ bmap,
    float* __restrict__ naux) {
  __shared__ float xs[256 * 36];  // 256 channels x 32 px, stride 36
  int t = threadIdx.x;
  int bi = blockIdx.y;
  int hw0 = blockIdx.x * 32;
  int co = t;
  float bias = bmap[co];
  float acc[32];
#pragma unroll
  for (int p = 0; p < 32; ++p) acc[p] = bias;

  for (int half = 0; half < 2; ++half) {
    const float* base = half ? aux : noisy;
    // stage 256 rows x 32 px
#pragma unroll
    for (int m = 0; m < 8; ++m) {
      int chunk = m * 256 + t;       // 0..2047
      int c = chunk >> 3, sub = chunk & 7;
      float4 val = *(const float4*)(base + (size_t)(bi * 256 + c) * HWSZ + hw0 + sub * 4);
      *(float4*)(xs + c * 36 + sub * 4) = val;
    }
    __syncthreads();
    for (int ci = 0; ci < 256; ++ci) {
      float w = wmapT[(half * 256 + ci) * 256 + co];
      const float* xr = xs + ci * 36;
#pragma unroll
      for (int m = 0; m < 8; ++m) {
        float4 xv = *(const float4*)(xr + m * 4);
        acc[m * 4 + 0] = fmaf(w, xv.x, acc[m * 4 + 0]);
        acc[m * 4 + 1] = fmaf(w, xv.y, acc[m * 4 + 1]);
        acc[m * 4 + 2] = fmaf(w, xv.z, acc[m * 4 + 2]);
        acc[m * 4 + 3] = fmaf(w, xv.w, acc[m * 4 + 3]);
      }
    }
    __syncthreads();
  }
  float* dst = naux + (size_t)(bi * 256 + co) * HWSZ + hw0;
#pragma unroll
  for (int m = 0; m < 8; ++m) {
    float4 o;
    o.x = fmaxf(acc[m * 4 + 0], 0.f);
    o.y = fmaxf(acc[m * 4 + 1], 0.f);
    o.z = fmaxf(acc[m * 4 + 2], 0.f);
    o.w = fmaxf(acc[m * 4 + 3], 0.f);
    *(float4*)(dst + m * 4) = o;
  }
}

// ---------------- K1b: q = 0.125*Wq@naux, k = Wk@naux, v = Wv@noisy ----------------
// outputs bf16, pixel-major [b][hw][256]
__global__ __launch_bounds__(256) void k_qkv(
    const float* __restrict__ naux, const float* __restrict__ noisy,
    const float* __restrict__ wqT, const float* __restrict__ wkT,
    const float* __restrict__ wvT,
    u16* __restrict__ q, u16* __restrict__ k, u16* __restrict__ v) {
  __shared__ float xbuf[256 * 36];
  int t = threadIdx.x;
  int bi = blockIdx.y;
  int hw0 = blockIdx.x * 32;
  int co = t;

  // stage n_aux (fp32) rows: thread t owns channel-row t
  {
    const float* src = naux + (size_t)(bi * 256 + t) * HWSZ + hw0;
#pragma unroll
    for (int m = 0; m < 8; ++m)
      *(float4*)(xbuf + t * 36 + m * 4) = *(const float4*)(src + m * 4);
  }
  __syncthreads();

  for (int pass = 0; pass < 2; ++pass) {
    const float* wT = pass == 0 ? wqT : wkT;
    float acc[32];
#pragma unroll
    for (int p = 0; p < 32; ++p) acc[p] = 0.f;
    for (int ci = 0; ci < 256; ++ci) {
      float w = wT[ci * 256 + co];
      const float* xr = xbuf + ci * 36;
#pragma unroll
      for (int m = 0; m < 8; ++m) {
        float4 xv = *(const float4*)(xr + m * 4);
        acc[m * 4 + 0] = fmaf(w, xv.x, acc[m * 4 + 0]);
        acc[m * 4 + 1] = fmaf(w, xv.y, acc[m * 4 + 1]);
        acc[m * 4 + 2] = fmaf(w, xv.z, acc[m * 4 + 2]);
        acc[m * 4 + 3] = fmaf(w, xv.w, acc[m * 4 + 3]);
      }
    }
    u16* dst = pass == 0 ? q : k;
    float scale = pass == 0 ? 0.125f : 1.f;
#pragma unroll
    for (int p = 0; p < 32; ++p)
      dst[((size_t)bi * HWSZ + hw0 + p) * 256 + co] = f2bf(acc[p] * scale);
  }

  __syncthreads();
  // restage noisy (fp32) for the v pass
#pragma unroll
  for (int m = 0; m < 8; ++m) {
    int chunk = m * 256 + t;
    int c = chunk >> 3, sub = chunk & 7;
    float4 val = *(const float4*)(noisy + (size_t)(bi * 256 + c) * HWSZ + hw0 + sub * 4);
    *(float4*)(xbuf + c * 36 + sub * 4) = val;
  }
  __syncthreads();
  {
    float acc[32];
#pragma unroll
    for (int p = 0; p < 32; ++p) acc[p] = 0.f;
    for (int ci = 0; ci < 256; ++ci) {
      float w = wvT[ci * 256 + co];
      const float* xr = xbuf + ci * 36;
#pragma unroll
      for (int m = 0; m < 8; ++m) {
        float4 xv = *(const float4*)(xr + m * 4);
        acc[m * 4 + 0] = fmaf(w, xv.x, acc[m * 4 + 0]);
        acc[m * 4 + 1] = fmaf(w, xv.y, acc[m * 4 + 1]);
        acc[m * 4 + 2] = fmaf(w, xv.z, acc[m * 4 + 2]);
        acc[m * 4 + 3] = fmaf(w, xv.w, acc[m * 4 + 3]);
      }
    }
#pragma unroll
    for (int p = 0; p < 32; ++p)
      v[((size_t)bi * HWSZ + hw0 + p) * 256 + co] = f2bf(acc[p]);
  }
}

// ---------------- K2: halo block attention ----------------
// one workgroup per (b, block, head); 25 queries x 121 keys x D=64
__global__ __launch_bounds__(256) void k_attn(
    const u16* __restrict__ q, const u16* __restrict__ k,
    const u16* __restrict__ v, const float* __restrict__ relh,
    const float* __restrict__ relw, float* __restrict__ out) {
  __shared__ float qs[28 * 64];    // rows 25..27 zero
  __shared__ u16 ksb[124 * 66];    // rows 121..123 zero, stride 66 (bank-safe)
  __shared__ u16 vsm[121 * 64];
  __shared__ float sim[28 * 124];
  __shared__ float rsum[25];

  int t = threadIdx.x;
  int bb = blockIdx.z;
  int head = blockIdx.y;
  int by = blockIdx.x / NB, bx = blockIdx.x % NB;

  // stage q (includes the 1/8 scale from K1b)
  for (int idx = t; idx < 28 * 64; idx += 256) {
    int i = idx >> 6, d = idx & 63;
    float val = 0.f;
    if (i < 25) {
      int y = by * 5 + i / 5, x = bx * 5 + i % 5;
      val = bf2f(q[((size_t)bb * HWSZ + y * 200 + x) * 256 + head * 64 + d]);
    }
    qs[idx] = val;
  }
  // stage k + rel (zero-padded halo gets rel only, matching the reference)
  for (int idx = t; idx < 124 * 64; idx += 256) {
    int j = idx >> 6, d = idx & 63;
    u16 val = 0;
    if (j < 121) {
      int ky = j / 11, kx = j - ky * 11;
      int y = by * 5 - 3 + ky, x = bx * 5 - 3 + kx;
      bool inb = (y >= 0) && (y < 200) && (x >= 0) && (x < 200);
      int yc = min(max(y, 0), 199), xc = min(max(x, 0), 199);
      float kv = bf2f(k[((size_t)bb * HWSZ + yc * 200 + xc) * 256 + head * 64 + d]);
      kv = inb ? kv : 0.f;
      float rel = (d < 32) ? relh[ky * 32 + d] : relw[kx * 32 + (d - 32)];
      val = f2bf(kv + rel);
    }
    ksb[j * 66 + d] = val;
  }
  // stage v (zero outside)
  for (int idx = t; idx < 121 * 64; idx += 256) {
    int j = idx >> 6, d = idx & 63;
    int ky = j / 11, kx = j - ky * 11;
    int y = by * 5 - 3 + ky, x = bx * 5 - 3 + kx;
    bool inb = (y >= 0) && (y < 200) && (x >= 0) && (x < 200);
    int yc = min(max(y, 0), 199), xc = min(max(x, 0), 199);
    u16 val = v[((size_t)bb * HWSZ + yc * 200 + xc) * 256 + head * 64 + d];
    vsm[j * 64 + d] = inb ? val : (u16)0;
  }
  __syncthreads();

  // sim = q . k^T, 4x4 register tiles over (i,j)
  if (t < 217) {
    int it = t / 31, jt = t % 31;
    float acc[4][4];
#pragma unroll
    for (int a = 0; a < 4; ++a)
#pragma unroll
      for (int c = 0; c < 4; ++c) acc[a][c] = 0.f;
    for (int d = 0; d < 64; ++d) {
      float qv[4], kv[4];
#pragma unroll
      for (int a = 0; a < 4; ++a) qv[a] = qs[(it + 7 * a) * 64 + d];
#pragma unroll
      for (int c = 0; c < 4; ++c) kv[c] = bf2f(ksb[(jt + 31 * c) * 66 + d]);
#pragma unroll
      for (int a = 0; a < 4; ++a)
#pragma unroll
        for (int c = 0; c < 4; ++c) acc[a][c] = fmaf(qv[a], kv[c], acc[a][c]);
    }
#pragma unroll
    for (int a = 0; a < 4; ++a)
#pragma unroll
      for (int c = 0; c < 4; ++c)
        sim[(it + 7 * a) * 124 + (jt + 31 * c)] = acc[a][c];
  }
  __syncthreads();

  // softmax over 121 keys; 8 lanes per row; store exp, keep 1/sum
  if (t < 200) {
    int i = t >> 3, s = t & 7;
    float m = -1e30f;
    for (int j = s; j < 121; j += 8) m = fmaxf(m, sim[i * 124 + j]);
    m = fmaxf(m, __shfl_xor(m, 1));
    m = fmaxf(m, __shfl_xor(m, 2));
    m = fmaxf(m, __shfl_xor(m, 4));
    float sum = 0.f;
    for (int j = s; j < 121; j += 8) {
      float e = __expf(sim[i * 124 + j] - m);
      sim[i * 124 + j] = e;
      sum += e;
    }
    sum += __shfl_xor(sum, 1);
    sum += __shfl_xor(sum, 2);
    sum += __shfl_xor(sum, 4);
    if (s == 0) rsum[i] = 1.f / sum;
  }
  __syncthreads();

  // out = (exp . v) * (1/sum); 4 rows x 2 channels per thread
  if (t < 224) {
    int it = t % 7, dt = t / 7;
    int d0 = dt * 2;
    float acc[4][2];
#pragma unroll
    for (int a = 0; a < 4; ++a) { acc[a][0] = 0.f; acc[a][1] = 0.f; }
    for (int j = 0; j < 121; ++j) {
      u32 vv = *(const u32*)(vsm + j * 64 + d0);
      float v0 = bflo(vv), v1 = bfhi(vv);
#pragma unroll
      for (int a = 0; a < 4; ++a) {
        float e = sim[(it + 7 * a) * 124 + j];
        acc[a][0] = fmaf(e, v0, acc[a][0]);
        acc[a][1] = fmaf(e, v1, acc[a][1]);
      }
    }
#pragma unroll
    for (int a = 0; a < 4; ++a) {
      int i = it + 7 * a;
      if (i < 25) {
        float r = rsum[i];
        int y = by * 5 + i / 5, x = bx * 5 + i % 5;
        size_t g = ((size_t)(bb * 256 + head * 64 + d0) * 200 + y) * 200 + x;
        out[g] = acc[a][0] * r;
        out[g + HWSZ] = acc[a][1] * r;
      }
    }
  }
}

extern "C" void kernel_launch(void* const* d_in, const int* in_sizes, int n_in,
                              void* d_out, int out_size, void* d_ws, size_t ws_size,
                              hipStream_t stream) {
  const float* noisy = (const float*)d_in[0];
  const float* aux   = (const float*)d_in[1];
  const float* Wmap  = (const float*)d_in[2];
  const float* bmap  = (const float*)d_in[3];
  const float* Wq    = (const float*)d_in[4];
  const float* Wk    = (const float*)d_in[5];
  const float* Wv    = (const float*)d_in[6];
  const float* relh  = (const float*)d_in[7];
  const float* relw  = (const float*)d_in[8];
  float* out = (float*)d_out;

  char* ws = (char*)d_ws;
  float* naux  = (float*)(ws);                    // 2*256*40000*4 = 81,920,000
  u16* q       = (u16*)(ws + 81920000);           // 40,960,000
  u16* k       = (u16*)(ws + 122880000);          // 40,960,000
  u16* v       = (u16*)(ws + 163840000);          // 40,960,000
  float* wmapT = (float*)(ws + 204800000);        // 524,288
  float* wqT   = (float*)(ws + 205324288);        // 262,144
  float* wkT   = (float*)(ws + 205586432);        // 262,144
  float* wvT   = (float*)(ws + 205848576);        // 262,144  (end ~206.1 MB)

  k_tw<<<dim3(512, 4), 256, 0, stream>>>(Wmap, Wq, Wk, Wv, wmapT, wqT, wkT, wvT);
  k_naux<<<dim3(1250, 2), 256, 0, stream>>>(noisy, aux, wmapT, bmap, naux);
  k_qkv<<<dim3(1250, 2), 256, 0, stream>>>(naux, noisy, wqT, wkT, wvT, q, k, v);
  k_attn<<<dim3(1600, 4, 2), 256, 0, stream>>>(q, k, v, relh, relw, out);
}

// Round 3
// 1028.909 us; speedup vs baseline: 1.5878x; 1.5878x over previous
//
#include <hip/hip_runtime.h>

typedef unsigned short u16;
typedef unsigned int u32;
typedef __attribute__((ext_vector_type(8))) short short8;
typedef __attribute__((ext_vector_type(4))) float floatx4;

#define HWSZ 40000
#define NB 40

__device__ __forceinline__ float bf2f(u16 x) {
  union { u32 u; float f; } c; c.u = ((u32)x) << 16; return c.f;
}
__device__ __forceinline__ float bflo(u32 u) {
  union { u32 u; float f; } c; c.u = u << 16; return c.f;
}
__device__ __forceinline__ float bfhi(u32 u) {
  union { u32 u; float f; } c; c.u = u & 0xffff0000u; return c.f;
}
__device__ __forceinline__ u16 f2bf(float f) {
  union { float f; u32 u; } c; c.f = f;
  u32 r = c.u + 0x7fffu + ((c.u >> 16) & 1u);
  return (u16)(r >> 16);
}

// ---------------- K0: weight fp32 -> bf16 cast (layout preserved [co][ci]) ----------------
__global__ __launch_bounds__(256) void k_tw(
    const float* __restrict__ Wmap, const float* __restrict__ Wq,
    const float* __restrict__ Wk, const float* __restrict__ Wv,
    u16* __restrict__ wmapB, u16* __restrict__ wqB,
    u16* __restrict__ wkB, u16* __restrict__ wvB) {
  int which = blockIdx.y;
  const float* src; u16* dst; int n;
  if (which == 0)      { src = Wmap; dst = wmapB; n = 131072; }
  else if (which == 1) { src = Wq;   dst = wqB;   n = 65536; }
  else if (which == 2) { src = Wk;   dst = wkB;   n = 65536; }
  else                 { src = Wv;   dst = wvB;   n = 65536; }
  int idx = blockIdx.x * 256 + threadIdx.x;
  if (idx < n) dst[idx] = f2bf(src[idx]);
}

// ---------------- K1a: n_aux = relu(W_map @ [noisy;aux] + b), bf16 MFMA ----------------
// output bf16 pixel-major [b][hw][256]
__global__ __launch_bounds__(256) void k_naux(
    const float* __restrict__ noisy, const float* __restrict__ aux,
    const u16* __restrict__ wmapB, const float* __restrict__ bmap,
    u16* __restrict__ naux) {
  __shared__ __align__(16) u16 xs[32 * 520];  // X tile [px][ci], ci=0..511
  __shared__ __align__(16) u16 os[32 * 264];  // out tile [px][co]
  int t = threadIdx.x;
  int bi = blockIdx.y;
  int hw0 = blockIdx.x * 32;
  int wave = t >> 6, lane = t & 63;
  int quad = lane >> 4, l16 = lane & 15;

  // stage X: fp32 channel-major -> bf16 [px][ci]
#pragma unroll
  for (int m = 0; m < 16; ++m) {
    int idx = m * 256 + t;            // 0..4095
    int ci = idx >> 3, sub = idx & 7; // 4 px per element-group
    const float* src = (ci < 256 ? noisy + (size_t)(bi * 256 + ci) * HWSZ
                                 : aux + (size_t)(bi * 256 + (ci - 256)) * HWSZ) + hw0 + sub * 4;
    float4 vx = *(const float4*)src;
    xs[(sub * 4 + 0) * 520 + ci] = f2bf(vx.x);
    xs[(sub * 4 + 1) * 520 + ci] = f2bf(vx.y);
    xs[(sub * 4 + 2) * 520 + ci] = f2bf(vx.z);
    xs[(sub * 4 + 3) * 520 + ci] = f2bf(vx.w);
  }
  __syncthreads();

  floatx4 acc[4][2];
#pragma unroll
  for (int mt = 0; mt < 4; ++mt)
#pragma unroll
    for (int nt = 0; nt < 2; ++nt) acc[mt][nt] = (floatx4){0.f, 0.f, 0.f, 0.f};

  // A row for this lane: co = wave*64 + mt*16 + l16, k-offset quad*8
  const u16* wbase = wmapB + (size_t)(wave * 64 + l16) * 512 + quad * 8;
#pragma unroll 4
  for (int ks = 0; ks < 16; ++ks) {
    short8 a[4], b[2];
#pragma unroll
    for (int mt = 0; mt < 4; ++mt)
      a[mt] = *(const short8*)(wbase + mt * 16 * 512 + ks * 32);
#pragma unroll
    for (int nt = 0; nt < 2; ++nt)
      b[nt] = *(const short8*)(&xs[(nt * 16 + l16) * 520 + ks * 32 + quad * 8]);
#pragma unroll
    for (int mt = 0; mt < 4; ++mt)
#pragma unroll
      for (int nt = 0; nt < 2; ++nt)
        acc[mt][nt] = __builtin_amdgcn_mfma_f32_16x16x32_bf16(a[mt], b[nt], acc[mt][nt], 0, 0, 0);
  }

  // epilogue: bias + relu -> bf16 -> os[px][co]   (C/D: col=l16=px, row=quad*4+r=co)
#pragma unroll
  for (int mt = 0; mt < 4; ++mt) {
#pragma unroll
    for (int r = 0; r < 4; ++r) {
      int co = wave * 64 + mt * 16 + quad * 4 + r;
      float bv = bmap[co];
#pragma unroll
      for (int nt = 0; nt < 2; ++nt) {
        int px = nt * 16 + l16;
        os[px * 264 + co] = f2bf(fmaxf(acc[mt][nt][r] + bv, 0.f));
      }
    }
  }
  __syncthreads();

  // coalesced store: os rows -> naux [b][hw][256]
#pragma unroll
  for (int m = 0; m < 4; ++m) {
    int idx = m * 256 + t;            // 0..1023
    int px = idx >> 5, sub = idx & 31;
    *(uint4*)(naux + ((size_t)bi * HWSZ + hw0 + px) * 256 + sub * 8) =
        *(const uint4*)(&os[px * 264 + sub * 8]);
  }
}

// ---------------- K1b: q,k from naux; v from noisy — bf16 MFMA ----------------
// outputs bf16 pixel-major [b][hw][256]
__global__ __launch_bounds__(256) void k_qkv(
    const u16* __restrict__ naux, const float* __restrict__ noisy,
    const u16* __restrict__ wqB, const u16* __restrict__ wkB,
    const u16* __restrict__ wvB,
    u16* __restrict__ q, u16* __restrict__ k, u16* __restrict__ v) {
  __shared__ __align__(16) u16 xs[32 * 264];  // X tile [px][ci], ci=0..255
  __shared__ __align__(16) u16 os[32 * 264];
  int t = threadIdx.x;
  int bi = blockIdx.y;
  int hw0 = blockIdx.x * 32;
  int wave = t >> 6, lane = t & 63;
  int quad = lane >> 4, l16 = lane & 15;

  // stage naux tile (already pixel-major bf16): straight copy
#pragma unroll
  for (int m = 0; m < 4; ++m) {
    int idx = m * 256 + t;
    int px = idx >> 5, sub = idx & 31;
    *(uint4*)(&xs[px * 264 + sub * 8]) =
        *(const uint4*)(naux + ((size_t)bi * HWSZ + hw0 + px) * 256 + sub * 8);
  }
  __syncthreads();

#pragma unroll 1
  for (int pass = 0; pass < 2; ++pass) {
    const u16* wb = (pass == 0 ? wqB : wkB) + (size_t)(wave * 64 + l16) * 256 + quad * 8;
    floatx4 acc[4][2];
#pragma unroll
    for (int mt = 0; mt < 4; ++mt)
#pragma unroll
      for (int nt = 0; nt < 2; ++nt) acc[mt][nt] = (floatx4){0.f, 0.f, 0.f, 0.f};
#pragma unroll 4
    for (int ks = 0; ks < 8; ++ks) {
      short8 a[4], b[2];
#pragma unroll
      for (int mt = 0; mt < 4; ++mt)
        a[mt] = *(const short8*)(wb + mt * 16 * 256 + ks * 32);
#pragma unroll
      for (int nt = 0; nt < 2; ++nt)
        b[nt] = *(const short8*)(&xs[(nt * 16 + l16) * 264 + ks * 32 + quad * 8]);
#pragma unroll
      for (int mt = 0; mt < 4; ++mt)
#pragma unroll
        for (int nt = 0; nt < 2; ++nt)
          acc[mt][nt] = __builtin_amdgcn_mfma_f32_16x16x32_bf16(a[mt], b[nt], acc[mt][nt], 0, 0, 0);
    }
    float scale = pass == 0 ? 0.125f : 1.f;
#pragma unroll
    for (int mt = 0; mt < 4; ++mt)
#pragma unroll
      for (int r = 0; r < 4; ++r) {
        int co = wave * 64 + mt * 16 + quad * 4 + r;
#pragma unroll
        for (int nt = 0; nt < 2; ++nt)
          os[(nt * 16 + l16) * 264 + co] = f2bf(acc[mt][nt][r] * scale);
      }
    __syncthreads();
    u16* dst = pass == 0 ? q : k;
#pragma unroll
    for (int m = 0; m < 4; ++m) {
      int idx = m * 256 + t;
      int px = idx >> 5, sub = idx & 31;
      *(uint4*)(dst + ((size_t)bi * HWSZ + hw0 + px) * 256 + sub * 8) =
          *(const uint4*)(&os[px * 264 + sub * 8]);
    }
    __syncthreads();
  }

  // restage xs from noisy (fp32 channel-major -> bf16 [px][ci])
#pragma unroll
  for (int m = 0; m < 8; ++m) {
    int idx = m * 256 + t;            // 0..2047
    int ci = idx >> 3, sub = idx & 7;
    const float* src = noisy + (size_t)(bi * 256 + ci) * HWSZ + hw0 + sub * 4;
    float4 vx = *(const float4*)src;
    xs[(sub * 4 + 0) * 264 + ci] = f2bf(vx.x);
    xs[(sub * 4 + 1) * 264 + ci] = f2bf(vx.y);
    xs[(sub * 4 + 2) * 264 + ci] = f2bf(vx.z);
    xs[(sub * 4 + 3) * 264 + ci] = f2bf(vx.w);
  }
  __syncthreads();
  {
    const u16* wb = wvB + (size_t)(wave * 64 + l16) * 256 + quad * 8;
    floatx4 acc[4][2];
#pragma unroll
    for (int mt = 0; mt < 4; ++mt)
#pragma unroll
      for (int nt = 0; nt < 2; ++nt) acc[mt][nt] = (floatx4){0.f, 0.f, 0.f, 0.f};
#pragma unroll 4
    for (int ks = 0; ks < 8; ++ks) {
      short8 a[4], b[2];
#pragma unroll
      for (int mt = 0; mt < 4; ++mt)
        a[mt] = *(const short8*)(wb + mt * 16 * 256 + ks * 32);
#pragma unroll
      for (int nt = 0; nt < 2; ++nt)
        b[nt] = *(const short8*)(&xs[(nt * 16 + l16) * 264 + ks * 32 + quad * 8]);
#pragma unroll
      for (int mt = 0; mt < 4; ++mt)
#pragma unroll
        for (int nt = 0; nt < 2; ++nt)
          acc[mt][nt] = __builtin_amdgcn_mfma_f32_16x16x32_bf16(a[mt], b[nt], acc[mt][nt], 0, 0, 0);
    }
#pragma unroll
    for (int mt = 0; mt < 4; ++mt)
#pragma unroll
      for (int r = 0; r < 4; ++r) {
        int co = wave * 64 + mt * 16 + quad * 4 + r;
#pragma unroll
        for (int nt = 0; nt < 2; ++nt)
          os[(nt * 16 + l16) * 264 + co] = f2bf(acc[mt][nt][r]);
      }
    __syncthreads();
#pragma unroll
    for (int m = 0; m < 4; ++m) {
      int idx = m * 256 + t;
      int px = idx >> 5, sub = idx & 31;
      *(uint4*)(v + ((size_t)bi * HWSZ + hw0 + px) * 256 + sub * 8) =
          *(const uint4*)(&os[px * 264 + sub * 8]);
    }
  }
}

// ---------------- K2: halo block attention (unchanged) ----------------
__global__ __launch_bounds__(256) void k_attn(
    const u16* __restrict__ q, const u16* __restrict__ k,
    const u16* __restrict__ v, const float* __restrict__ relh,
    const float* __restrict__ relw, float* __restrict__ out) {
  __shared__ float qs[28 * 64];
  __shared__ u16 ksb[124 * 66];
  __shared__ u16 vsm[121 * 64];
  __shared__ float sim[28 * 124];
  __shared__ float rsum[25];

  int t = threadIdx.x;
  int bb = blockIdx.z;
  int head = blockIdx.y;
  int by = blockIdx.x / NB, bx = blockIdx.x % NB;

  for (int idx = t; idx < 28 * 64; idx += 256) {
    int i = idx >> 6, d = idx & 63;
    float val = 0.f;
    if (i < 25) {
      int y = by * 5 + i / 5, x = bx * 5 + i % 5;
      val = bf2f(q[((size_t)bb * HWSZ + y * 200 + x) * 256 + head * 64 + d]);
    }
    qs[idx] = val;
  }
  for (int idx = t; idx < 124 * 64; idx += 256) {
    int j = idx >> 6, d = idx & 63;
    u16 val = 0;
    if (j < 121) {
      int ky = j / 11, kx = j - ky * 11;
      int y = by * 5 - 3 + ky, x = bx * 5 - 3 + kx;
      bool inb = (y >= 0) && (y < 200) && (x >= 0) && (x < 200);
      int yc = min(max(y, 0), 199), xc = min(max(x, 0), 199);
      float kv = bf2f(k[((size_t)bb * HWSZ + yc * 200 + xc) * 256 + head * 64 + d]);
      kv = inb ? kv : 0.f;
      float rel = (d < 32) ? relh[ky * 32 + d] : relw[kx * 32 + (d - 32)];
      val = f2bf(kv + rel);
    }
    ksb[j * 66 + d] = val;
  }
  for (int idx = t; idx < 121 * 64; idx += 256) {
    int j = idx >> 6, d = idx & 63;
    int ky = j / 11, kx = j - ky * 11;
    int y = by * 5 - 3 + ky, x = bx * 5 - 3 + kx;
    bool inb = (y >= 0) && (y < 200) && (x >= 0) && (x < 200);
    int yc = min(max(y, 0), 199), xc = min(max(x, 0), 199);
    u16 val = v[((size_t)bb * HWSZ + yc * 200 + xc) * 256 + head * 64 + d];
    vsm[j * 64 + d] = inb ? val : (u16)0;
  }
  __syncthreads();

  if (t < 217) {
    int it = t / 31, jt = t % 31;
    float acc[4][4];
#pragma unroll
    for (int a = 0; a < 4; ++a)
#pragma unroll
      for (int c = 0; c < 4; ++c) acc[a][c] = 0.f;
    for (int d = 0; d < 64; ++d) {
      float qv[4], kv[4];
#pragma unroll
      for (int a = 0; a < 4; ++a) qv[a] = qs[(it + 7 * a) * 64 + d];
#pragma unroll
      for (int c = 0; c < 4; ++c) kv[c] = bf2f(ksb[(jt + 31 * c) * 66 + d]);
#pragma unroll
      for (int a = 0; a < 4; ++a)
#pragma unroll
        for (int c = 0; c < 4; ++c) acc[a][c] = fmaf(qv[a], kv[c], acc[a][c]);
    }
#pragma unroll
    for (int a = 0; a < 4; ++a)
#pragma unroll
      for (int c = 0; c < 4; ++c)
        sim[(it + 7 * a) * 124 + (jt + 31 * c)] = acc[a][c];
  }
  __syncthreads();

  if (t < 200) {
    int i = t >> 3, s = t & 7;
    float m = -1e30f;
    for (int j = s; j < 121; j += 8) m = fmaxf(m, sim[i * 124 + j]);
    m = fmaxf(m, __shfl_xor(m, 1));
    m = fmaxf(m, __shfl_xor(m, 2));
    m = fmaxf(m, __shfl_xor(m, 4));
    float sum = 0.f;
    for (int j = s; j < 121; j += 8) {
      float e = __expf(sim[i * 124 + j] - m);
      sim[i * 124 + j] = e;
      sum += e;
    }
    sum += __shfl_xor(sum, 1);
    sum += __shfl_xor(sum, 2);
    sum += __shfl_xor(sum, 4);
    if (s == 0) rsum[i] = 1.f / sum;
  }
  __syncthreads();

  if (t < 224) {
    int it = t % 7, dt = t / 7;
    int d0 = dt * 2;
    float acc[4][2];
#pragma unroll
    for (int a = 0; a < 4; ++a) { acc[a][0] = 0.f; acc[a][1] = 0.f; }
    for (int j = 0; j < 121; ++j) {
      u32 vv = *(const u32*)(vsm + j * 64 + d0);
      float v0 = bflo(vv), v1 = bfhi(vv);
#pragma unroll
      for (int a = 0; a < 4; ++a) {
        float e = sim[(it + 7 * a) * 124 + j];
        acc[a][0] = fmaf(e, v0, acc[a][0]);
        acc[a][1] = fmaf(e, v1, acc[a][1]);
      }
    }
#pragma unroll
    for (int a = 0; a < 4; ++a) {
      int i = it + 7 * a;
      if (i < 25) {
        float r = rsum[i];
        int y = by * 5 + i / 5, x = bx * 5 + i % 5;
        size_t g = ((size_t)(bb * 256 + head * 64 + d0) * 200 + y) * 200 + x;
        out[g] = acc[a][0] * r;
        out[g + HWSZ] = acc[a][1] * r;
      }
    }
  }
}

extern "C" void kernel_launch(void* const* d_in, const int* in_sizes, int n_in,
                              void* d_out, int out_size, void* d_ws, size_t ws_size,
                              hipStream_t stream) {
  const float* noisy = (const float*)d_in[0];
  const float* aux   = (const float*)d_in[1];
  const float* Wmap  = (const float*)d_in[2];
  const float* bmap  = (const float*)d_in[3];
  const float* Wq    = (const float*)d_in[4];
  const float* Wk    = (const float*)d_in[5];
  const float* Wv    = (const float*)d_in[6];
  const float* relh  = (const float*)d_in[7];
  const float* relw  = (const float*)d_in[8];
  float* out = (float*)d_out;

  char* ws = (char*)d_ws;
  u16* naux  = (u16*)(ws);                   // 2*40000*256*2 = 40,960,000
  u16* q     = (u16*)(ws + 40960000);        // 40,960,000
  u16* k     = (u16*)(ws + 81920000);        // 40,960,000
  u16* v     = (u16*)(ws + 122880000);       // 40,960,000
  u16* wmapB = (u16*)(ws + 163840000);       // 262,144
  u16* wqB   = (u16*)(ws + 164102144);       // 131,072
  u16* wkB   = (u16*)(ws + 164233216);       // 131,072
  u16* wvB   = (u16*)(ws + 164364288);       // 131,072 (end ~164.5 MB)

  k_tw<<<dim3(512, 4), 256, 0, stream>>>(Wmap, Wq, Wk, Wv, wmapB, wqB, wkB, wvB);
  k_naux<<<dim3(1250, 2), 256, 0, stream>>>(noisy, aux, wmapB, bmap, naux);
  k_qkv<<<dim3(1250, 2), 256, 0, stream>>>(naux, noisy, wqB, wkB, wvB, q, k, v);
  k_attn<<<dim3(1600, 4, 2), 256, 0, stream>>>(q, k, v, relh, relw, out);
}

// Round 4
// 736.326 us; speedup vs baseline: 2.2187x; 1.3974x over previous
//
#include <hip/hip_runtime.h>

typedef unsigned short u16;
typedef unsigned int u32;
typedef _Float16 f16;
typedef __attribute__((ext_vector_type(8))) _Float16 half8;
typedef __attribute__((ext_vector_type(4))) float floatx4;

#define HWSZ 40000
#define NB 40

__device__ __forceinline__ u16 f2h(float f) {
  union { f16 h; u16 u; } c; c.h = (f16)f; return c.u;
}

// ---------------- K0: weight fp32 -> fp16 cast + rel table ----------------
__global__ __launch_bounds__(256) void k_tw(
    const float* __restrict__ Wmap, const float* __restrict__ Wq,
    const float* __restrict__ Wk, const float* __restrict__ Wv,
    const float* __restrict__ relh, const float* __restrict__ relw,
    u16* __restrict__ wmapB, u16* __restrict__ wqB,
    u16* __restrict__ wkB, u16* __restrict__ wvB, u16* __restrict__ relB) {
  int which = blockIdx.y;
  int idx = blockIdx.x * 256 + threadIdx.x;
  if (which == 4) {
    // relB[j][d], j=0..127 (rows >=121 zero), d=0..63
    if (idx < 8192) {
      int j = idx >> 6, d = idx & 63;
      float val = 0.f;
      if (j < 121) {
        int ky = j / 11, kx = j - ky * 11;
        val = (d < 32) ? relh[ky * 32 + d] : relw[kx * 32 + (d - 32)];
      }
      relB[idx] = f2h(val);
    }
    return;
  }
  const float* src; u16* dst; int n;
  if (which == 0)      { src = Wmap; dst = wmapB; n = 131072; }
  else if (which == 1) { src = Wq;   dst = wqB;   n = 65536; }
  else if (which == 2) { src = Wk;   dst = wkB;   n = 65536; }
  else                 { src = Wv;   dst = wvB;   n = 65536; }
  if (idx < n) dst[idx] = f2h(src[idx]);
}

// ---------------- K1a: n_aux = relu(W_map @ [noisy;aux] + b), f16 MFMA ----------------
// output fp16 pixel-major [b][hw][256]
__global__ __launch_bounds__(256) void k_naux(
    const float* __restrict__ noisy, const float* __restrict__ aux,
    const u16* __restrict__ wmapB, const float* __restrict__ bmap,
    u16* __restrict__ naux) {
  __shared__ __align__(16) u16 xs[32 * 520];
  __shared__ __align__(16) u16 os[32 * 264];
  int t = threadIdx.x;
  int bi = blockIdx.y;
  int hw0 = blockIdx.x * 32;
  int wave = t >> 6, lane = t & 63;
  int quad = lane >> 4, l16 = lane & 15;

#pragma unroll
  for (int m = 0; m < 16; ++m) {
    int idx = m * 256 + t;
    int ci = idx >> 3, sub = idx & 7;
    const float* src = (ci < 256 ? noisy + (size_t)(bi * 256 + ci) * HWSZ
                                 : aux + (size_t)(bi * 256 + (ci - 256)) * HWSZ) + hw0 + sub * 4;
    float4 vx = *(const float4*)src;
    xs[(sub * 4 + 0) * 520 + ci] = f2h(vx.x);
    xs[(sub * 4 + 1) * 520 + ci] = f2h(vx.y);
    xs[(sub * 4 + 2) * 520 + ci] = f2h(vx.z);
    xs[(sub * 4 + 3) * 520 + ci] = f2h(vx.w);
  }
  __syncthreads();

  floatx4 acc[4][2];
#pragma unroll
  for (int mt = 0; mt < 4; ++mt)
#pragma unroll
    for (int nt = 0; nt < 2; ++nt) acc[mt][nt] = (floatx4){0.f, 0.f, 0.f, 0.f};

  const u16* wbase = wmapB + (size_t)(wave * 64 + l16) * 512 + quad * 8;
#pragma unroll 4
  for (int ks = 0; ks < 16; ++ks) {
    half8 a[4], b[2];
#pragma unroll
    for (int mt = 0; mt < 4; ++mt)
      a[mt] = *(const half8*)(wbase + mt * 16 * 512 + ks * 32);
#pragma unroll
    for (int nt = 0; nt < 2; ++nt)
      b[nt] = *(const half8*)(&xs[(nt * 16 + l16) * 520 + ks * 32 + quad * 8]);
#pragma unroll
    for (int mt = 0; mt < 4; ++mt)
#pragma unroll
      for (int nt = 0; nt < 2; ++nt)
        acc[mt][nt] = __builtin_amdgcn_mfma_f32_16x16x32_f16(a[mt], b[nt], acc[mt][nt], 0, 0, 0);
  }

#pragma unroll
  for (int mt = 0; mt < 4; ++mt) {
#pragma unroll
    for (int r = 0; r < 4; ++r) {
      int co = wave * 64 + mt * 16 + quad * 4 + r;
      float bv = bmap[co];
#pragma unroll
      for (int nt = 0; nt < 2; ++nt) {
        int px = nt * 16 + l16;
        os[px * 264 + co] = f2h(fmaxf(acc[mt][nt][r] + bv, 0.f));
      }
    }
  }
  __syncthreads();

#pragma unroll
  for (int m = 0; m < 4; ++m) {
    int idx = m * 256 + t;
    int px = idx >> 5, sub = idx & 31;
    *(uint4*)(naux + ((size_t)bi * HWSZ + hw0 + px) * 256 + sub * 8) =
        *(const uint4*)(&os[px * 264 + sub * 8]);
  }
}

// ---------------- K1b: q,k from naux; v from noisy — f16 MFMA ----------------
// outputs fp16 pixel-major [b][hw][256]
__global__ __launch_bounds__(256) void k_qkv(
    const u16* __restrict__ naux, const float* __restrict__ noisy,
    const u16* __restrict__ wqB, const u16* __restrict__ wkB,
    const u16* __restrict__ wvB,
    u16* __restrict__ q, u16* __restrict__ k, u16* __restrict__ v) {
  __shared__ __align__(16) u16 xs[32 * 264];
  __shared__ __align__(16) u16 os[32 * 264];
  int t = threadIdx.x;
  int bi = blockIdx.y;
  int hw0 = blockIdx.x * 32;
  int wave = t >> 6, lane = t & 63;
  int quad = lane >> 4, l16 = lane & 15;

#pragma unroll
  for (int m = 0; m < 4; ++m) {
    int idx = m * 256 + t;
    int px = idx >> 5, sub = idx & 31;
    *(uint4*)(&xs[px * 264 + sub * 8]) =
        *(const uint4*)(naux + ((size_t)bi * HWSZ + hw0 + px) * 256 + sub * 8);
  }
  __syncthreads();

#pragma unroll 1
  for (int pass = 0; pass < 2; ++pass) {
    const u16* wb = (pass == 0 ? wqB : wkB) + (size_t)(wave * 64 + l16) * 256 + quad * 8;
    floatx4 acc[4][2];
#pragma unroll
    for (int mt = 0; mt < 4; ++mt)
#pragma unroll
      for (int nt = 0; nt < 2; ++nt) acc[mt][nt] = (floatx4){0.f, 0.f, 0.f, 0.f};
#pragma unroll 4
    for (int ks = 0; ks < 8; ++ks) {
      half8 a[4], b[2];
#pragma unroll
      for (int mt = 0; mt < 4; ++mt)
        a[mt] = *(const half8*)(wb + mt * 16 * 256 + ks * 32);
#pragma unroll
      for (int nt = 0; nt < 2; ++nt)
        b[nt] = *(const half8*)(&xs[(nt * 16 + l16) * 264 + ks * 32 + quad * 8]);
#pragma unroll
      for (int mt = 0; mt < 4; ++mt)
#pragma unroll
        for (int nt = 0; nt < 2; ++nt)
          acc[mt][nt] = __builtin_amdgcn_mfma_f32_16x16x32_f16(a[mt], b[nt], acc[mt][nt], 0, 0, 0);
    }
    float scale = pass == 0 ? 0.125f : 1.f;
#pragma unroll
    for (int mt = 0; mt < 4; ++mt)
#pragma unroll
      for (int r = 0; r < 4; ++r) {
        int co = wave * 64 + mt * 16 + quad * 4 + r;
#pragma unroll
        for (int nt = 0; nt < 2; ++nt)
          os[(nt * 16 + l16) * 264 + co] = f2h(acc[mt][nt][r] * scale);
      }
    __syncthreads();
    u16* dst = pass == 0 ? q : k;
#pragma unroll
    for (int m = 0; m < 4; ++m) {
      int idx = m * 256 + t;
      int px = idx >> 5, sub = idx & 31;
      *(uint4*)(dst + ((size_t)bi * HWSZ + hw0 + px) * 256 + sub * 8) =
          *(const uint4*)(&os[px * 264 + sub * 8]);
    }
    __syncthreads();
  }

#pragma unroll
  for (int m = 0; m < 8; ++m) {
    int idx = m * 256 + t;
    int ci = idx >> 3, sub = idx & 7;
    const float* src = noisy + (size_t)(bi * 256 + ci) * HWSZ + hw0 + sub * 4;
    float4 vx = *(const float4*)src;
    xs[(sub * 4 + 0) * 264 + ci] = f2h(vx.x);
    xs[(sub * 4 + 1) * 264 + ci] = f2h(vx.y);
    xs[(sub * 4 + 2) * 264 + ci] = f2h(vx.z);
    xs[(sub * 4 + 3) * 264 + ci] = f2h(vx.w);
  }
  __syncthreads();
  {
    const u16* wb = wvB + (size_t)(wave * 64 + l16) * 256 + quad * 8;
    floatx4 acc[4][2];
#pragma unroll
    for (int mt = 0; mt < 4; ++mt)
#pragma unroll
      for (int nt = 0; nt < 2; ++nt) acc[mt][nt] = (floatx4){0.f, 0.f, 0.f, 0.f};
#pragma unroll 4
    for (int ks = 0; ks < 8; ++ks) {
      half8 a[4], b[2];
#pragma unroll
      for (int mt = 0; mt < 4; ++mt)
        a[mt] = *(const half8*)(wb + mt * 16 * 256 + ks * 32);
#pragma unroll
      for (int nt = 0; nt < 2; ++nt)
        b[nt] = *(const half8*)(&xs[(nt * 16 + l16) * 264 + ks * 32 + quad * 8]);
#pragma unroll
      for (int mt = 0; mt < 4; ++mt)
#pragma unroll
        for (int nt = 0; nt < 2; ++nt)
          acc[mt][nt] = __builtin_amdgcn_mfma_f32_16x16x32_f16(a[mt], b[nt], acc[mt][nt], 0, 0, 0);
    }
#pragma unroll
    for (int mt = 0; mt < 4; ++mt)
#pragma unroll
      for (int r = 0; r < 4; ++r) {
        int co = wave * 64 + mt * 16 + quad * 4 + r;
#pragma unroll
        for (int nt = 0; nt < 2; ++nt)
          os[(nt * 16 + l16) * 264 + co] = f2h(acc[mt][nt][r]);
      }
    __syncthreads();
#pragma unroll
    for (int m = 0; m < 4; ++m) {
      int idx = m * 256 + t;
      int px = idx >> 5, sub = idx & 31;
      *(uint4*)(v + ((size_t)bi * HWSZ + hw0 + px) * 256 + sub * 8) =
          *(const uint4*)(&os[px * 264 + sub * 8]);
    }
  }
}

// ---------------- K2: halo block attention — f16 MFMA, 1 wave per (b,block,head) ----------------
__global__ __launch_bounds__(64) void k_attn(
    const u16* __restrict__ q, const u16* __restrict__ k,
    const u16* __restrict__ v, const u16* __restrict__ relB,
    float* __restrict__ out) {
  // fragment-swizzled LDS: each b128 read is lane-sequential (conflict-free)
  __shared__ __align__(16) u16 vt[16 * 512];   // V^T frags: [ntd*4+ks][lane][8]  (16 KB)
  __shared__ __align__(16) u16 pf[8 * 512];    // P frags:   [mt*4+ks][lane][8]   (8 KB)

  int t = threadIdx.x;           // single wave
  int bb = blockIdx.z;
  int head = blockIdx.y;
  int by = blockIdx.x / NB, bx = blockIdx.x % NB;
  int l16 = t & 15, quad = t >> 4;
  int hi = l16 >> 3, lowl = l16 & 7;

  const size_t hbase = (size_t)bb * HWSZ;
  const int hoff = head * 64;

  // ---- stage V^T into vt (frag-swizzled), j=0..127 x d=0..63 in chunks of 8 d ----
#pragma unroll 4
  for (int it = 0; it < 16; ++it) {
    int idx = it * 64 + t;       // 0..1023
    int j = idx >> 3, c8 = idx & 7;
    int jc = min(j, 120);
    int ky = jc / 11, kx = jc - ky * 11;
    int y = by * 5 - 3 + ky, x = bx * 5 - 3 + kx;
    bool inb = (j <= 120) && (y >= 0) && (y < 200) && (x >= 0) && (x < 200);
    int yc = min(max(y, 0), 199), xc = min(max(x, 0), 199);
    uint4 raw = *(const uint4*)(v + (hbase + yc * 200 + xc) * 256 + hoff + c8 * 8);
    if (!inb) raw = (uint4){0, 0, 0, 0};
    u32 w[4] = {raw.x, raw.y, raw.z, raw.w};
    int base16 = ((c8 >> 1) * 4 + (j >> 5)) * 512 + ((((j >> 3) & 3) * 16 + (c8 & 1) * 8) * 8) + (j & 7);
#pragma unroll
    for (int i = 0; i < 8; ++i) {
      u16 val = (u16)((i & 1) ? (w[i >> 1] >> 16) : (w[i >> 1] & 0xffffu));
      vt[base16 + i * 8] = val;
    }
  }

  // ---- Q a-frags from global (lane l16 = query row, clamped) ----
  half8 aq[2][2];
#pragma unroll
  for (int mt = 0; mt < 2; ++mt) {
    int i = min(mt * 16 + l16, 24);
    int y = by * 5 + i / 5, x = bx * 5 + i % 5;
    const u16* qb = q + (hbase + y * 200 + x) * 256 + hoff;
#pragma unroll
    for (int ks = 0; ks < 2; ++ks)
      aq[mt][ks] = *(const half8*)(qb + ks * 32 + quad * 8);
  }

  // ---- S = Q.K^T + Q.Rel^T ----
  floatx4 acc[2][8];
#pragma unroll
  for (int mt = 0; mt < 2; ++mt)
#pragma unroll
    for (int nt = 0; nt < 8; ++nt) acc[mt][nt] = (floatx4){0.f, 0.f, 0.f, 0.f};

#pragma unroll 2
  for (int nt = 0; nt < 8; ++nt) {
    int j = nt * 16 + l16;
    int jc = min(j, 120);
    int ky = jc / 11, kx = jc - ky * 11;
    int y = by * 5 - 3 + ky, x = bx * 5 - 3 + kx;
    bool inb = (y >= 0) && (y < 200) && (x >= 0) && (x < 200);
    int yc = min(max(y, 0), 199), xc = min(max(x, 0), 199);
    const u16* kb = k + (hbase + yc * 200 + xc) * 256 + hoff;
    const u16* rb = relB + jc * 64;
#pragma unroll
    for (int ks = 0; ks < 2; ++ks) {
      uint4 raw = *(const uint4*)(kb + ks * 32 + quad * 8);
      if (!inb) raw = (uint4){0, 0, 0, 0};
      union { uint4 u; half8 h; } kc; kc.u = raw;
      half8 rl = *(const half8*)(rb + ks * 32 + quad * 8);
#pragma unroll
      for (int mt = 0; mt < 2; ++mt) {
        acc[mt][nt] = __builtin_amdgcn_mfma_f32_16x16x32_f16(aq[mt][ks], kc.h, acc[mt][nt], 0, 0, 0);
        acc[mt][nt] = __builtin_amdgcn_mfma_f32_16x16x32_f16(aq[mt][ks], rl, acc[mt][nt], 0, 0, 0);
      }
    }
  }
  __syncthreads();  // vt staged (also orders vt before PV reads)

  // ---- softmax in registers + write P frags ----
  float rinv[2][4];
#pragma unroll
  for (int mt = 0; mt < 2; ++mt) {
#pragma unroll
    for (int r = 0; r < 4; ++r) {
      float vmax = acc[mt][0][r];
#pragma unroll
      for (int nt = 1; nt < 7; ++nt) vmax = fmaxf(vmax, acc[mt][nt][r]);
      float x7 = (l16 < 9) ? acc[mt][7][r] : -INFINITY;
      vmax = fmaxf(vmax, x7);
#pragma unroll
      for (int off = 1; off < 16; off <<= 1)
        vmax = fmaxf(vmax, __shfl_xor(vmax, off, 16));
      float es[8], sum = 0.f;
#pragma unroll
      for (int nt = 0; nt < 7; ++nt) { es[nt] = __expf(acc[mt][nt][r] - vmax); sum += es[nt]; }
      es[7] = (l16 < 9) ? __expf(acc[mt][7][r] - vmax) : 0.f;
      sum += es[7];
#pragma unroll
      for (int off = 1; off < 16; off <<= 1)
        sum += __shfl_xor(sum, off, 16);
      rinv[mt][r] = 1.f / sum;
      int arow = quad * 4 + r;
#pragma unroll
      for (int nt = 0; nt < 8; ++nt) {
        int a16 = (mt * 4 + (nt >> 1)) * 512 + ((((nt & 1) * 2 + hi) * 16 + arow) * 8) + lowl;
        pf[a16] = f2h(es[nt]);
      }
    }
  }
  __syncthreads();  // pf written

  // ---- O = P.V ----
  floatx4 o[2][4];
#pragma unroll
  for (int mt = 0; mt < 2; ++mt)
#pragma unroll
    for (int nd = 0; nd < 4; ++nd) o[mt][nd] = (floatx4){0.f, 0.f, 0.f, 0.f};
#pragma unroll
  for (int ks = 0; ks < 4; ++ks) {
    half8 a[2], b[4];
#pragma unroll
    for (int mt = 0; mt < 2; ++mt)
      a[mt] = *(const half8*)(&pf[(mt * 4 + ks) * 512 + t * 8]);
#pragma unroll
    for (int nd = 0; nd < 4; ++nd)
      b[nd] = *(const half8*)(&vt[(nd * 4 + ks) * 512 + t * 8]);
#pragma unroll
    for (int mt = 0; mt < 2; ++mt)
#pragma unroll
      for (int nd = 0; nd < 4; ++nd)
        o[mt][nd] = __builtin_amdgcn_mfma_f32_16x16x32_f16(a[mt], b[nd], o[mt][nd], 0, 0, 0);
  }

  // ---- epilogue: scale by 1/sum, store ----
#pragma unroll
  for (int mt = 0; mt < 2; ++mt) {
#pragma unroll
    for (int r = 0; r < 4; ++r) {
      int i = mt * 16 + quad * 4 + r;
      if (i < 25) {
        int y = by * 5 + i / 5, x = bx * 5 + i % 5;
        float rs = rinv[mt][r];
#pragma unroll
        for (int nd = 0; nd < 4; ++nd) {
          int c = hoff + nd * 16 + l16;
          out[((size_t)(bb * 256 + c)) * HWSZ + y * 200 + x] = o[mt][nd][r] * rs;
        }
      }
    }
  }
}

extern "C" void kernel_launch(void* const* d_in, const int* in_sizes, int n_in,
                              void* d_out, int out_size, void* d_ws, size_t ws_size,
                              hipStream_t stream) {
  const float* noisy = (const float*)d_in[0];
  const float* aux   = (const float*)d_in[1];
  const float* Wmap  = (const float*)d_in[2];
  const float* bmap  = (const float*)d_in[3];
  const float* Wq    = (const float*)d_in[4];
  const float* Wk    = (const float*)d_in[5];
  const float* Wv    = (const float*)d_in[6];
  const float* relh  = (const float*)d_in[7];
  const float* relw  = (const float*)d_in[8];
  float* out = (float*)d_out;

  char* ws = (char*)d_ws;
  u16* naux  = (u16*)(ws);                   // 40,960,000
  u16* q     = (u16*)(ws + 40960000);        // 40,960,000
  u16* k     = (u16*)(ws + 81920000);        // 40,960,000
  u16* v     = (u16*)(ws + 122880000);       // 40,960,000
  u16* wmapB = (u16*)(ws + 163840000);       // 262,144
  u16* wqB   = (u16*)(ws + 164102144);       // 131,072
  u16* wkB   = (u16*)(ws + 164233216);       // 131,072
  u16* wvB   = (u16*)(ws + 164364288);       // 131,072
  u16* relB  = (u16*)(ws + 164495360);       // 16,384 (end ~164.5 MB)

  k_tw<<<dim3(512, 5), 256, 0, stream>>>(Wmap, Wq, Wk, Wv, relh, relw,
                                         wmapB, wqB, wkB, wvB, relB);
  k_naux<<<dim3(1250, 2), 256, 0, stream>>>(noisy, aux, wmapB, bmap, naux);
  k_qkv<<<dim3(1250, 2), 256, 0, stream>>>(naux, noisy, wqB, wkB, wvB, q, k, v);
  k_attn<<<dim3(1600, 4, 2), 64, 0, stream>>>(q, k, v, relB, out);
}